// Round 14
// baseline (870.213 us; speedup 1.0000x reference)
//
#include <hip/hip_runtime.h>

#define NN 100000
#define NCELL 40000
#define NDRUG 60000
#define EE 1600000
#define FEPS 1e-5f
#define SLOPE 0.2f
#define NB 391    // dst-buckets (256 rows each)
#define SCH 8192  // edges per sort block
#define SNB 196   // ceil(EE/SCH)

typedef unsigned short ushort_t;
typedef unsigned int uint_t;
typedef __attribute__((ext_vector_type(8))) __bf16 bf16x8;
typedef __attribute__((ext_vector_type(4))) float f32x4;

__device__ __forceinline__ ushort_t f2bf(float x) {
  uint_t u = __float_as_uint(x);
  u = (u + 0x7FFFu + ((u >> 16) & 1u)) >> 16;  // RNE
  return (ushort_t)u;
}
__device__ __forceinline__ uint_t pack2bf(float a, float b) {
  return (uint_t)f2bf(a) | ((uint_t)f2bf(b) << 16);
}
__device__ __forceinline__ float bf2f(ushort_t x) {
  return __uint_as_float(((uint_t)x) << 16);
}

// ---------------------------------------------------------------- converts
__global__ __launch_bounds__(256) void feat_cvt_k(const float* __restrict__ X,
                                                  ushort_t* __restrict__ Y, int n8) {
  int i = blockIdx.x * 256 + threadIdx.x;
  if (i >= n8) return;
  const float4* in4 = (const float4*)X;
  float4 a = in4[2 * i], b = in4[2 * i + 1];
  uint4 o;
  o.x = pack2bf(a.x, a.y); o.y = pack2bf(a.z, a.w);
  o.z = pack2bf(b.x, b.y); o.w = pack2bf(b.z, b.w);
  ((uint4*)Y)[i] = o;
}

struct WC { const float* s; ushort_t* d; int K; };
struct WCA { WC w[6]; };
// Wt[col][k] = bf16(W[k][col]); grid (6, maxK/16), block 128 (one col per thread)
__global__ __launch_bounds__(128) void wcvt_k(WCA a) {
  const WC wc = a.w[blockIdx.x];
  const int k0 = blockIdx.y * 16;
  if (k0 >= wc.K) return;
  const int col = threadIdx.x;
  const int k1 = min(k0 + 16, wc.K);
  for (int k = k0; k < k1; k++)
    wc.d[(size_t)col * wc.K + k] = f2bf(wc.s[(size_t)k * 128 + col]);
}

// ---- CSR build: deterministic bucket partition, zero global atomics ----
__global__ __launch_bounds__(256) void sort_count_k(const int* __restrict__ dst,
                                                    int* __restrict__ tbl, int E) {
  __shared__ int cnt[NB];
  const int blk = blockIdx.x;
  for (int i = threadIdx.x; i < NB; i += 256) cnt[i] = 0;
  __syncthreads();
  const int e0 = blk * SCH, e1 = min(e0 + SCH, E);
  for (int e = e0 + threadIdx.x; e < e1; e += 256) atomicAdd(&cnt[dst[e] >> 8], 1);
  __syncthreads();
  for (int i = threadIdx.x; i < NB; i += 256) tbl[i * SNB + blk] = cnt[i];
}

__global__ __launch_bounds__(256) void bkt_total_k(const int* __restrict__ tbl,
                                                   int* __restrict__ total) {
  __shared__ int sm[256];
  const int b = blockIdx.x;
  const int t = threadIdx.x;
  sm[t] = (t < SNB) ? tbl[b * SNB + t] : 0;
  __syncthreads();
  for (int off = 128; off > 0; off >>= 1) {
    if (t < off) sm[t] += sm[t + off];
    __syncthreads();
  }
  if (t == 0) total[b] = sm[0];
}

__global__ __launch_bounds__(512) void bkt_scan_k(const int* __restrict__ total,
                                                  int* __restrict__ bktoff,
                                                  int* __restrict__ rowp, int n, int E) {
  __shared__ int sm[512];
  const int t = threadIdx.x;
  const int v = (t < NB) ? total[t] : 0;
  sm[t] = v;
  __syncthreads();
  for (int off = 1; off < 512; off <<= 1) {
    int u = (t >= off) ? sm[t - off] : 0;
    __syncthreads();
    sm[t] += u;
    __syncthreads();
  }
  if (t < NB) bktoff[t] = sm[t] - v;
  if (t == 0) { bktoff[NB] = E; rowp[n] = E; }
}

__global__ __launch_bounds__(256) void sort_offset_k(const int* __restrict__ tbl,
                                                     const int* __restrict__ bktoff,
                                                     int* __restrict__ off) {
  __shared__ int sm[256];
  const int b = blockIdx.x;
  const int t = threadIdx.x;
  const int v = (t < SNB) ? tbl[b * SNB + t] : 0;
  sm[t] = v;
  __syncthreads();
  for (int o = 1; o < 256; o <<= 1) {
    int u = (t >= o) ? sm[t - o] : 0;
    __syncthreads();
    sm[t] += u;
    __syncthreads();
  }
  if (t < SNB) off[b * SNB + t] = bktoff[b] + sm[t] - v;
}

__global__ __launch_bounds__(256) void sort_place_k(const int* __restrict__ src,
                                                    const int* __restrict__ dst,
                                                    const int* __restrict__ off,
                                                    uint_t* __restrict__ ebuf, int E) {
  __shared__ int pos[NB];
  const int blk = blockIdx.x;
  for (int i = threadIdx.x; i < NB; i += 256) pos[i] = off[i * SNB + blk];
  __syncthreads();
  const int e0 = blk * SCH, e1 = min(e0 + SCH, E);
  for (int e = e0 + threadIdx.x; e < e1; e += 256) {
    const int d = dst[e];
    const int p = atomicAdd(&pos[d >> 8], 1);
    ebuf[p] = (uint_t)src[e] | ((uint_t)(d & 255) << 17);
  }
}

__global__ __launch_bounds__(256) void bucket_fill2_k(const uint_t* __restrict__ ebuf,
                                                      const int* __restrict__ bktoff,
                                                      int* __restrict__ rowp,
                                                      float* __restrict__ dis,
                                                      int* __restrict__ esrc, int n) {
  __shared__ int hist[256];
  __shared__ int scn[256];
  const int b = blockIdx.x;
  const int t = threadIdx.x;
  const int r0 = b << 8;
  const int base = bktoff[b];
  const int end = bktoff[b + 1];
  hist[t] = 0;
  __syncthreads();
  for (int i = base + t; i < end; i += 256)
    atomicAdd(&hist[ebuf[i] >> 17], 1);
  __syncthreads();
  const int d = hist[t];
  scn[t] = d;
  __syncthreads();
  for (int off = 1; off < 256; off <<= 1) {
    int u = (t >= off) ? scn[t - off] : 0;
    __syncthreads();
    scn[t] += u;
    __syncthreads();
  }
  const int excl = scn[t] - d;
  const int r = r0 + t;
  if (r < n) {
    rowp[r] = base + excl;
    dis[r] = (d > 0) ? rsqrtf((float)d) : 0.f;
  }
  __syncthreads();
  hist[t] = excl;  // reuse as cursors
  __syncthreads();
  for (int i = base + t; i < end; i += 256) {
    const uint_t v = ebuf[i];
    const int rl = (int)(v >> 17);
    const int p = atomicAdd(&hist[rl], 1);
    esrc[base + p] = (int)(v & 0x1FFFFu);
  }
}

// ---------------------------------------------------------------- MFMA GEMM
#define SWZ(base, row, byte) ((char*)(base) + (((row)*256 + (byte)) ^ (((row)&7) << 4)))
__global__ __launch_bounds__(256) void gemm_mfma_k(const ushort_t* __restrict__ X0,
                                                   const ushort_t* __restrict__ X1,
                                                   const ushort_t* __restrict__ X2,
                                                   const ushort_t* __restrict__ Wt,
                                                   const float* __restrict__ bias,
                                                   float* __restrict__ Yf,
                                                   ushort_t* __restrict__ Yb,
                                                   int nrows, int nseg, int act) {
  __shared__ ushort_t sA[128 * 128];
  __shared__ ushort_t sB[128 * 128];
  const int t = threadIdx.x;
  const int wave = t >> 6;
  const int lane = t & 63;
  const int lane15 = lane & 15;
  const int lgrp = lane >> 4;  // 0..3
  const int row0 = blockIdx.x * 128;
  const int Ktot = nseg * 128;

  const int tr = t >> 1;
  const int th = (t & 1) * 64;
  const int ra = min(row0 + tr, nrows - 1);
  const int wb = th * 2;

  f32x4 acc[2][8];
#pragma unroll
  for (int m = 0; m < 2; m++)
#pragma unroll
    for (int f = 0; f < 8; f++) acc[m][f] = (f32x4)0.f;

  for (int seg = 0; seg < nseg; seg++) {
    const ushort_t* Xp = (seg == 0) ? X0 : ((seg == 1) ? X1 : X2);
    const ushort_t* Ap = Xp + (size_t)ra * 128 + th;
    const ushort_t* Bp = Wt + (size_t)tr * Ktot + (seg << 7) + th;
    const uint4 a0 = *(const uint4*)(Ap + 0);
    const uint4 a1 = *(const uint4*)(Ap + 8);
    const uint4 a2 = *(const uint4*)(Ap + 16);
    const uint4 a3 = *(const uint4*)(Ap + 24);
    const uint4 a4 = *(const uint4*)(Ap + 32);
    const uint4 a5 = *(const uint4*)(Ap + 40);
    const uint4 a6 = *(const uint4*)(Ap + 48);
    const uint4 a7 = *(const uint4*)(Ap + 56);
    const uint4 b0 = *(const uint4*)(Bp + 0);
    const uint4 b1 = *(const uint4*)(Bp + 8);
    const uint4 b2 = *(const uint4*)(Bp + 16);
    const uint4 b3 = *(const uint4*)(Bp + 24);
    const uint4 b4 = *(const uint4*)(Bp + 32);
    const uint4 b5 = *(const uint4*)(Bp + 40);
    const uint4 b6 = *(const uint4*)(Bp + 48);
    const uint4 b7 = *(const uint4*)(Bp + 56);
    __syncthreads();
    *(uint4*)SWZ(sA, tr, wb + 0) = a0;
    *(uint4*)SWZ(sA, tr, wb + 16) = a1;
    *(uint4*)SWZ(sA, tr, wb + 32) = a2;
    *(uint4*)SWZ(sA, tr, wb + 48) = a3;
    *(uint4*)SWZ(sA, tr, wb + 64) = a4;
    *(uint4*)SWZ(sA, tr, wb + 80) = a5;
    *(uint4*)SWZ(sA, tr, wb + 96) = a6;
    *(uint4*)SWZ(sA, tr, wb + 112) = a7;
    *(uint4*)SWZ(sB, tr, wb + 0) = b0;
    *(uint4*)SWZ(sB, tr, wb + 16) = b1;
    *(uint4*)SWZ(sB, tr, wb + 32) = b2;
    *(uint4*)SWZ(sB, tr, wb + 48) = b3;
    *(uint4*)SWZ(sB, tr, wb + 64) = b4;
    *(uint4*)SWZ(sB, tr, wb + 80) = b5;
    *(uint4*)SWZ(sB, tr, wb + 96) = b6;
    *(uint4*)SWZ(sB, tr, wb + 112) = b7;
    __syncthreads();
#pragma unroll
    for (int kk = 0; kk < 4; kk++) {
      const int cb = kk * 64 + lgrp * 16;
      const int rA0 = wave * 32 + lane15;
      bf16x8 av0 = *(const bf16x8*)SWZ(sA, rA0, cb);
      bf16x8 av1 = *(const bf16x8*)SWZ(sA, rA0 + 16, cb);
#pragma unroll
      for (int f = 0; f < 8; f++) {
        bf16x8 wv = *(const bf16x8*)SWZ(sB, f * 16 + lane15, cb);
        acc[0][f] = __builtin_amdgcn_mfma_f32_16x16x32_bf16(av0, wv, acc[0][f], 0, 0, 0);
        acc[1][f] = __builtin_amdgcn_mfma_f32_16x16x32_bf16(av1, wv, acc[1][f], 0, 0, 0);
      }
    }
  }

  const int row0w = row0 + wave * 32;
#pragma unroll
  for (int m = 0; m < 2; m++) {
    const int rbase = row0w + m * 16 + lgrp * 4;
#pragma unroll
    for (int f = 0; f < 8; f++) {
      const int col = f * 16 + lane15;
      const float bv = bias ? bias[col] : 0.f;
#pragma unroll
      for (int j = 0; j < 4; j++) {
        const int r = rbase + j;
        if (r < nrows) {
          float o = acc[m][f][j] + bv;
          if (act == 1) o = o > 0.f ? o : SLOPE * o;
          else if (act == 2) o = o > 0.f ? o : 0.f;
          if (Yf) Yf[(size_t)r * 128 + col] = o;
          else Yb[(size_t)r * 128 + col] = f2bf(o);
        }
      }
    }
  }
}

// ---------------------------------------------------------------- gather (bf16)
// Wave per dst row; 4 slots x 16 lanes; each slot processes edge pairs (j, j+4)
// with stride 8 -> 8 independent row-reads in flight per wave (2x MLP vs R13).
// dr is hoisted: accumulate sum(dis[s]*x[s]); multiply by dr after reduce.
__global__ __launch_bounds__(256) void gcn_gather_k(const ushort_t* __restrict__ xw,
                                                    const int* __restrict__ rowp,
                                                    const int* __restrict__ esrc,
                                                    const float* __restrict__ dis,
                                                    const float* __restrict__ bias,
                                                    ushort_t* __restrict__ out, int nrows) {
  const int lane = threadIdx.x & 63;
  const int row = (blockIdx.x * blockDim.x + threadIdx.x) >> 6;
  if (row >= nrows) return;
  const int slot = lane >> 4;
  const int ch = lane & 15;        // channels ch*8 .. ch*8+7
  const int start = rowp[row];
  const int end = rowp[row + 1];
  const float dr = dis[row];

  float a0 = 0.f, a1 = 0.f, a2 = 0.f, a3 = 0.f, a4 = 0.f, a5 = 0.f, a6 = 0.f, a7 = 0.f;
  for (int j = start + slot; j < end; j += 8) {
    const int s1 = esrc[j];
    const int j2 = j + 4;
    const bool h2 = j2 < end;
    const int s2 = h2 ? esrc[j2] : s1;
    const float w1 = dis[s1];
    const float w2 = h2 ? dis[s2] : 0.f;
    const uint4 v1 = *(const uint4*)(xw + (size_t)s1 * 128 + ch * 8);
    const uint4 v2 = *(const uint4*)(xw + (size_t)s2 * 128 + ch * 8);
    a0 += w1 * __uint_as_float(v1.x << 16) + w2 * __uint_as_float(v2.x << 16);
    a1 += w1 * __uint_as_float(v1.x & 0xFFFF0000u) + w2 * __uint_as_float(v2.x & 0xFFFF0000u);
    a2 += w1 * __uint_as_float(v1.y << 16) + w2 * __uint_as_float(v2.y << 16);
    a3 += w1 * __uint_as_float(v1.y & 0xFFFF0000u) + w2 * __uint_as_float(v2.y & 0xFFFF0000u);
    a4 += w1 * __uint_as_float(v1.z << 16) + w2 * __uint_as_float(v2.z << 16);
    a5 += w1 * __uint_as_float(v1.z & 0xFFFF0000u) + w2 * __uint_as_float(v2.z & 0xFFFF0000u);
    a6 += w1 * __uint_as_float(v1.w << 16) + w2 * __uint_as_float(v2.w << 16);
    a7 += w1 * __uint_as_float(v1.w & 0xFFFF0000u) + w2 * __uint_as_float(v2.w & 0xFFFF0000u);
  }
  a0 += __shfl_xor(a0, 16, 64); a1 += __shfl_xor(a1, 16, 64);
  a2 += __shfl_xor(a2, 16, 64); a3 += __shfl_xor(a3, 16, 64);
  a4 += __shfl_xor(a4, 16, 64); a5 += __shfl_xor(a5, 16, 64);
  a6 += __shfl_xor(a6, 16, 64); a7 += __shfl_xor(a7, 16, 64);
  a0 += __shfl_xor(a0, 32, 64); a1 += __shfl_xor(a1, 32, 64);
  a2 += __shfl_xor(a2, 32, 64); a3 += __shfl_xor(a3, 32, 64);
  a4 += __shfl_xor(a4, 32, 64); a5 += __shfl_xor(a5, 32, 64);
  a6 += __shfl_xor(a6, 32, 64); a7 += __shfl_xor(a7, 32, 64);

  if (slot == 0) {
    const float4 b0 = *(const float4*)(bias + ch * 8);
    const float4 b1 = *(const float4*)(bias + ch * 8 + 4);
    float o0 = dr * a0 + b0.x, o1 = dr * a1 + b0.y;
    float o2 = dr * a2 + b0.z, o3 = dr * a3 + b0.w;
    float o4 = dr * a4 + b1.x, o5 = dr * a5 + b1.y;
    float o6 = dr * a6 + b1.z, o7 = dr * a7 + b1.w;
    o0 = o0 > 0.f ? o0 : SLOPE * o0; o1 = o1 > 0.f ? o1 : SLOPE * o1;
    o2 = o2 > 0.f ? o2 : SLOPE * o2; o3 = o3 > 0.f ? o3 : SLOPE * o3;
    o4 = o4 > 0.f ? o4 : SLOPE * o4; o5 = o5 > 0.f ? o5 : SLOPE * o5;
    o6 = o6 > 0.f ? o6 : SLOPE * o6; o7 = o7 > 0.f ? o7 : SLOPE * o7;
    uint4 o;
    o.x = pack2bf(o0, o1); o.y = pack2bf(o2, o3);
    o.z = pack2bf(o4, o5); o.w = pack2bf(o6, o7);
    *(uint4*)(out + (size_t)row * 128 + ch * 8) = o;
  }
}

// ---------------------------------------------------------------- batchnorm
__global__ __launch_bounds__(256) void bn_stats_k(const ushort_t* __restrict__ X,
                                                  float* __restrict__ sums,
                                                  float* __restrict__ sumsq, int nrows) {
  __shared__ float ls[256], lq[256];
  const int t = threadIdx.x;
  const int c = t & 127;
  const int h = t >> 7;
  const int r0 = blockIdx.x * 256;
  const int r1 = min(r0 + 256, nrows);
  float s = 0.f, q = 0.f;
  for (int r = r0 + h; r < r1; r += 2) {
    float v = bf2f(X[(size_t)r * 128 + c]);
    s += v;
    q += v * v;
  }
  ls[t] = s;
  lq[t] = q;
  __syncthreads();
  if (t < 128) {
    s = ls[t] + ls[t + 128];
    q = lq[t] + lq[t + 128];
    atomicAdd(&sums[c], s);
    atomicAdd(&sumsq[c], q);
  }
}

__global__ void bn_finalize_k(const float* __restrict__ sums,
                              const float* __restrict__ sumsq,
                              const float* __restrict__ g,
                              const float* __restrict__ be,
                              float* __restrict__ scl, float* __restrict__ sht) {
  int c = threadIdx.x;
  float mu = sums[c] * (1.f / (float)NN);
  float var = sumsq[c] * (1.f / (float)NN) - mu * mu;
  float s = g[c] * rsqrtf(var + FEPS);
  scl[c] = s;
  sht[c] = be[c] - mu * s;
}

// fold BN affine into head weight
__global__ __launch_bounds__(128) void fold_head_k(const float* __restrict__ W,
                                                   const float* __restrict__ b,
                                                   const float* __restrict__ sclS,
                                                   const float* __restrict__ shtS,
                                                   const float* __restrict__ sclR,
                                                   const float* __restrict__ shtR,
                                                   ushort_t* __restrict__ Wf,
                                                   float* __restrict__ bf) {
  const int col = threadIdx.x;
  float acc = b[col];
  for (int k = 0; k < 256; k++) {
    const float w = W[(size_t)k * 128 + col];
    const float sc = (k < 128) ? sclS[k] : sclR[k - 128];
    const float sh = (k < 128) ? shtS[k] : shtR[k - 128];
    acc += sh * w;
    Wf[(size_t)col * 256 + k] = f2bf(sc * w);
  }
  bf[col] = acc;
}

// ---------------------------------------------------------------- launch
extern "C" void kernel_launch(void* const* d_in, const int* in_sizes, int n_in,
                              void* d_out, int out_size, void* d_ws, size_t ws_size,
                              hipStream_t stream) {
  const float* feature = (const float*)d_in[0];
  const int* sen_edge = (const int*)d_in[1];
  const int* res_edge = (const int*)d_in[2];
  const float* W_sen1 = (const float*)d_in[3];
  const float* b_sen1 = (const float*)d_in[4];
  const float* W_sen2 = (const float*)d_in[5];
  const float* b_sen2 = (const float*)d_in[6];
  const float* W_senfc = (const float*)d_in[7];
  const float* b_senfc = (const float*)d_in[8];
  const float* g_sen = (const float*)d_in[9];
  const float* be_sen = (const float*)d_in[10];
  const float* W_res1 = (const float*)d_in[11];
  const float* b_res1 = (const float*)d_in[12];
  const float* W_res2 = (const float*)d_in[13];
  const float* b_res2 = (const float*)d_in[14];
  const float* W_resfc = (const float*)d_in[15];
  const float* b_resfc = (const float*)d_in[16];
  const float* g_res = (const float*)d_in[17];
  const float* be_res = (const float*)d_in[18];
  const float* W_cell = (const float*)d_in[19];
  const float* b_cell = (const float*)d_in[20];
  const float* W_drug = (const float*)d_in[21];
  const float* b_drug = (const float*)d_in[22];
  float* out = (float*)d_out;

  const size_t NF = (size_t)NN * 128;
  char* wsb = (char*)d_ws;
  ushort_t* featb = (ushort_t*)wsb;                 // NF bf16 each
  ushort_t* x1b = featb + NF;
  ushort_t* x2b = x1b + NF;
  ushort_t* xwb = x2b + NF;
  ushort_t* xallSb = xwb + NF;
  ushort_t* xallRb = xallSb + NF;
  ushort_t* wt = xallRb + NF;                       // weight pool
  ushort_t* W1tS = wt;                              // 128*128
  ushort_t* W2tS = W1tS + 128 * 128;
  ushort_t* WfctS = W2tS + 128 * 128;               // 128*384
  ushort_t* W1tR = WfctS + 128 * 384;
  ushort_t* W2tR = W1tR + 128 * 128;
  ushort_t* WfctR = W2tR + 128 * 128;
  ushort_t* Wcellf = WfctR + 128 * 384;             // 128*256 (folded)
  ushort_t* Wdrugf = Wcellf + 128 * 256;
  float* dis = (float*)(Wdrugf + 128 * 256);        // NN
  int* rowp = (int*)(dis + NN);                     // NN+1
  int* esrc = rowp + (NN + 1);                      // EE
  uint_t* ebuf = (uint_t*)(esrc + EE);              // EE
  int* tbl = (int*)(ebuf + EE);                     // NB*SNB
  int* off = tbl + NB * SNB;                        // NB*SNB
  int* total = off + NB * SNB;                      // NB
  int* bktoff = total + NB;                         // NB+1
  float* sums = (float*)(bktoff + NB + 1);          // 128
  float* sumsq = sums + 128;
  float* sclS = sumsq + 128;
  float* shtS = sclS + 128;
  float* sclR = shtS + 128;
  float* shtR = sclR + 128;
  float* bcellf = shtR + 128;
  float* bdrugf = bcellf + 128;

  const int MG = (NN + 127) / 128;          // 782
  const int GATH_N = (NN * 64 + 255) / 256; // 25000
  const int STAT_N = (NN + 255) / 256;      // 391

  feat_cvt_k<<<(int)(NF / 8 + 255) / 256, 256, 0, stream>>>(feature, featb, (int)(NF / 8));
  WCA wa;
  wa.w[0] = {W_sen1, W1tS, 128};  wa.w[1] = {W_sen2, W2tS, 128};
  wa.w[2] = {W_senfc, WfctS, 384}; wa.w[3] = {W_res1, W1tR, 128};
  wa.w[4] = {W_res2, W2tR, 128};  wa.w[5] = {W_resfc, WfctR, 384};
  wcvt_k<<<dim3(6, 24), 128, 0, stream>>>(wa);

  struct Branch {
    const int* edge;
    ushort_t* W1t; const float* b1;
    ushort_t* W2t; const float* b2;
    ushort_t* Wfct; const float* bfc;
    const float* g; const float* be;
    ushort_t* xallb; float* scl; float* sht;
  };
  Branch br[2] = {
      {sen_edge, W1tS, b_sen1, W2tS, b_sen2, WfctS, b_senfc, g_sen, be_sen, xallSb, sclS, shtS},
      {res_edge, W1tR, b_res1, W2tR, b_res2, WfctR, b_resfc, g_res, be_res, xallRb, sclR, shtR},
  };

  for (int b = 0; b < 2; b++) {
    const int* src = br[b].edge;
    const int* dst = br[b].edge + EE;
    // CSR build: no global atomics anywhere
    sort_count_k<<<SNB, 256, 0, stream>>>(dst, tbl, EE);
    bkt_total_k<<<NB, 256, 0, stream>>>(tbl, total);
    bkt_scan_k<<<1, 512, 0, stream>>>(total, bktoff, rowp, NN, EE);
    sort_offset_k<<<NB, 256, 0, stream>>>(tbl, bktoff, off);
    sort_place_k<<<SNB, 256, 0, stream>>>(src, dst, off, ebuf, EE);
    bucket_fill2_k<<<NB, 256, 0, stream>>>(ebuf, bktoff, rowp, dis, esrc, NN);
    // layer 1
    gemm_mfma_k<<<MG, 256, 0, stream>>>(featb, nullptr, nullptr, br[b].W1t, nullptr,
                                        nullptr, xwb, NN, 1, 0);
    gcn_gather_k<<<GATH_N, 256, 0, stream>>>(xwb, rowp, esrc, dis, br[b].b1, x1b, NN);
    // layer 2
    gemm_mfma_k<<<MG, 256, 0, stream>>>(x1b, nullptr, nullptr, br[b].W2t, nullptr,
                                        nullptr, xwb, NN, 1, 0);
    gcn_gather_k<<<GATH_N, 256, 0, stream>>>(xwb, rowp, esrc, dis, br[b].b2, x2b, NN);
    // fc
    gemm_mfma_k<<<MG, 256, 0, stream>>>(featb, x1b, x2b, br[b].Wfct, br[b].bfc,
                                        nullptr, br[b].xallb, NN, 3, 2);
    // batchnorm stats
    (void)hipMemsetAsync(sums, 0, 2 * 128 * sizeof(float), stream);
    bn_stats_k<<<STAT_N, 256, 0, stream>>>(br[b].xallb, sums, sumsq, NN);
    bn_finalize_k<<<1, 128, 0, stream>>>(sums, sumsq, br[b].g, br[b].be, br[b].scl, br[b].sht);
  }

  fold_head_k<<<1, 128, 0, stream>>>(W_cell, b_cell, sclS, shtS, sclR, shtR, Wcellf, bcellf);
  fold_head_k<<<1, 128, 0, stream>>>(W_drug, b_drug, sclS, shtS, sclR, shtR, Wdrugf, bdrugf);
  const int MGC = (NCELL + 127) / 128;
  const int MGD = (NDRUG + 127) / 128;
  gemm_mfma_k<<<MGC, 256, 0, stream>>>(xallSb, xallRb, nullptr, Wcellf, bcellf,
                                       out, nullptr, NCELL, 2, 2);
  float* outD = out + (size_t)NCELL * 128;
  gemm_mfma_k<<<MGD, 256, 0, stream>>>(xallSb + (size_t)NCELL * 128, xallRb + (size_t)NCELL * 128,
                                       nullptr, Wdrugf, bdrugf, outD, nullptr, NDRUG, 2, 2);
}

// Round 15
// 820.292 us; speedup vs baseline: 1.0609x; 1.0609x over previous
//
#include <hip/hip_runtime.h>

#define NN 100000
#define NCELL 40000
#define NDRUG 60000
#define EE 1600000
#define FEPS 1e-5f
#define SLOPE 0.2f
#define NB 391    // dst-buckets (256 rows each)
#define SCH 8192  // edges per sort block
#define SNB 196   // ceil(EE/SCH)

typedef unsigned short ushort_t;
typedef unsigned int uint_t;
typedef __attribute__((ext_vector_type(8))) __bf16 bf16x8;
typedef __attribute__((ext_vector_type(4))) float f32x4;
typedef __attribute__((ext_vector_type(2))) float f32x2;

__device__ __forceinline__ ushort_t f2bf(float x) {
  uint_t u = __float_as_uint(x);
  u = (u + 0x7FFFu + ((u >> 16) & 1u)) >> 16;  // RNE
  return (ushort_t)u;
}
__device__ __forceinline__ uint_t pack2bf(float a, float b) {
  return (uint_t)f2bf(a) | ((uint_t)f2bf(b) << 16);
}
__device__ __forceinline__ float bf2f(ushort_t x) {
  return __uint_as_float(((uint_t)x) << 16);
}
__device__ __forceinline__ f32x2 u2f2(uint_t u) {
  f32x2 r;
  r.x = __uint_as_float(u << 16);
  r.y = __uint_as_float(u & 0xFFFF0000u);
  return r;
}

// ---------------------------------------------------------------- converts
__global__ __launch_bounds__(256) void feat_cvt_k(const float* __restrict__ X,
                                                  ushort_t* __restrict__ Y, int n8) {
  int i = blockIdx.x * 256 + threadIdx.x;
  if (i >= n8) return;
  const float4* in4 = (const float4*)X;
  float4 a = in4[2 * i], b = in4[2 * i + 1];
  uint4 o;
  o.x = pack2bf(a.x, a.y); o.y = pack2bf(a.z, a.w);
  o.z = pack2bf(b.x, b.y); o.w = pack2bf(b.z, b.w);
  ((uint4*)Y)[i] = o;
}

struct WC { const float* s; ushort_t* d; int K; };
struct WCA { WC w[6]; };
__global__ __launch_bounds__(128) void wcvt_k(WCA a) {
  const WC wc = a.w[blockIdx.x];
  const int k0 = blockIdx.y * 16;
  if (k0 >= wc.K) return;
  const int col = threadIdx.x;
  const int k1 = min(k0 + 16, wc.K);
  for (int k = k0; k < k1; k++)
    wc.d[(size_t)col * wc.K + k] = f2bf(wc.s[(size_t)k * 128 + col]);
}

// ---- CSR build: deterministic bucket partition, zero global atomics ----
__global__ __launch_bounds__(256) void sort_count_k(const int* __restrict__ dst,
                                                    int* __restrict__ tbl, int E) {
  __shared__ int cnt[NB];
  const int blk = blockIdx.x;
  for (int i = threadIdx.x; i < NB; i += 256) cnt[i] = 0;
  __syncthreads();
  const int e0 = blk * SCH, e1 = min(e0 + SCH, E);
  for (int e = e0 + threadIdx.x; e < e1; e += 256) atomicAdd(&cnt[dst[e] >> 8], 1);
  __syncthreads();
  for (int i = threadIdx.x; i < NB; i += 256) tbl[i * SNB + blk] = cnt[i];
}

__global__ __launch_bounds__(256) void bkt_total_k(const int* __restrict__ tbl,
                                                   int* __restrict__ total) {
  __shared__ int sm[256];
  const int b = blockIdx.x;
  const int t = threadIdx.x;
  sm[t] = (t < SNB) ? tbl[b * SNB + t] : 0;
  __syncthreads();
  for (int off = 128; off > 0; off >>= 1) {
    if (t < off) sm[t] += sm[t + off];
    __syncthreads();
  }
  if (t == 0) total[b] = sm[0];
}

__global__ __launch_bounds__(512) void bkt_scan_k(const int* __restrict__ total,
                                                  int* __restrict__ bktoff,
                                                  int* __restrict__ rowp, int n, int E) {
  __shared__ int sm[512];
  const int t = threadIdx.x;
  const int v = (t < NB) ? total[t] : 0;
  sm[t] = v;
  __syncthreads();
  for (int off = 1; off < 512; off <<= 1) {
    int u = (t >= off) ? sm[t - off] : 0;
    __syncthreads();
    sm[t] += u;
    __syncthreads();
  }
  if (t < NB) bktoff[t] = sm[t] - v;
  if (t == 0) { bktoff[NB] = E; rowp[n] = E; }
}

__global__ __launch_bounds__(256) void sort_offset_k(const int* __restrict__ tbl,
                                                     const int* __restrict__ bktoff,
                                                     int* __restrict__ off) {
  __shared__ int sm[256];
  const int b = blockIdx.x;
  const int t = threadIdx.x;
  const int v = (t < SNB) ? tbl[b * SNB + t] : 0;
  sm[t] = v;
  __syncthreads();
  for (int o = 1; o < 256; o <<= 1) {
    int u = (t >= o) ? sm[t - o] : 0;
    __syncthreads();
    sm[t] += u;
    __syncthreads();
  }
  if (t < SNB) off[b * SNB + t] = bktoff[b] + sm[t] - v;
}

__global__ __launch_bounds__(256) void sort_place_k(const int* __restrict__ src,
                                                    const int* __restrict__ dst,
                                                    const int* __restrict__ off,
                                                    uint_t* __restrict__ ebuf, int E) {
  __shared__ int pos[NB];
  const int blk = blockIdx.x;
  for (int i = threadIdx.x; i < NB; i += 256) pos[i] = off[i * SNB + blk];
  __syncthreads();
  const int e0 = blk * SCH, e1 = min(e0 + SCH, E);
  for (int e = e0 + threadIdx.x; e < e1; e += 256) {
    const int d = dst[e];
    const int p = atomicAdd(&pos[d >> 8], 1);
    ebuf[p] = (uint_t)src[e] | ((uint_t)(d & 255) << 17);
  }
}

__global__ __launch_bounds__(256) void bucket_fill2_k(const uint_t* __restrict__ ebuf,
                                                      const int* __restrict__ bktoff,
                                                      int* __restrict__ rowp,
                                                      float* __restrict__ dis,
                                                      int* __restrict__ esrc, int n) {
  __shared__ int hist[256];
  __shared__ int scn[256];
  const int b = blockIdx.x;
  const int t = threadIdx.x;
  const int r0 = b << 8;
  const int base = bktoff[b];
  const int end = bktoff[b + 1];
  hist[t] = 0;
  __syncthreads();
  for (int i = base + t; i < end; i += 256)
    atomicAdd(&hist[ebuf[i] >> 17], 1);
  __syncthreads();
  const int d = hist[t];
  scn[t] = d;
  __syncthreads();
  for (int off = 1; off < 256; off <<= 1) {
    int u = (t >= off) ? scn[t - off] : 0;
    __syncthreads();
    scn[t] += u;
    __syncthreads();
  }
  const int excl = scn[t] - d;
  const int r = r0 + t;
  if (r < n) {
    rowp[r] = base + excl;
    dis[r] = (d > 0) ? rsqrtf((float)d) : 0.f;
  }
  __syncthreads();
  hist[t] = excl;  // reuse as cursors
  __syncthreads();
  for (int i = base + t; i < end; i += 256) {
    const uint_t v = ebuf[i];
    const int rl = (int)(v >> 17);
    const int p = atomicAdd(&hist[rl], 1);
    esrc[base + p] = (int)(v & 0x1FFFFu);
  }
}

// augment: per-edge (byte offset, dis[src]) pairs -> removes dependent dis load
// from the 2 hot gathers per branch.
__global__ __launch_bounds__(256) void esrc_aug_k(const int* __restrict__ esrc,
                                                  const float* __restrict__ dis,
                                                  int2* __restrict__ esrc2, int E) {
  int i = blockIdx.x * 256 + threadIdx.x;
  if (i >= E) return;
  const int s = esrc[i];
  esrc2[i] = make_int2(s * 256, __float_as_int(dis[s]));
}

// ---------------------------------------------------------------- MFMA GEMM
// LDS rows 256B, XOR swizzle on write+read (stage); epilogue bounces acc through
// LDS (128x130 f32, 2-way-free banks) for coalesced uint4 C stores.
#define SWZ(base, row, byte) ((char*)(base) + (((row)*256 + (byte)) ^ (((row)&7) << 4)))
#define FST 130
__global__ __launch_bounds__(256) void gemm_mfma_k(const ushort_t* __restrict__ X0,
                                                   const ushort_t* __restrict__ X1,
                                                   const ushort_t* __restrict__ X2,
                                                   const ushort_t* __restrict__ Wt,
                                                   const float* __restrict__ bias,
                                                   float* __restrict__ Yf,
                                                   ushort_t* __restrict__ Yb,
                                                   int nrows, int nseg, int act) {
  __shared__ ushort_t smem[128 * FST * 2];  // 66560B; stage uses first 64KB
  ushort_t* sA = smem;
  ushort_t* sB = smem + 128 * 128;
  const int t = threadIdx.x;
  const int wave = t >> 6;
  const int lane = t & 63;
  const int lane15 = lane & 15;
  const int lgrp = lane >> 4;  // 0..3
  const int row0 = blockIdx.x * 128;
  const int Ktot = nseg * 128;

  const int tr = t >> 1;
  const int th = (t & 1) * 64;
  const int ra = min(row0 + tr, nrows - 1);
  const int wb = th * 2;

  f32x4 acc[2][8];
#pragma unroll
  for (int m = 0; m < 2; m++)
#pragma unroll
    for (int f = 0; f < 8; f++) acc[m][f] = (f32x4)0.f;

  for (int seg = 0; seg < nseg; seg++) {
    const ushort_t* Xp = (seg == 0) ? X0 : ((seg == 1) ? X1 : X2);
    const ushort_t* Ap = Xp + (size_t)ra * 128 + th;
    const ushort_t* Bp = Wt + (size_t)tr * Ktot + (seg << 7) + th;
    const uint4 a0 = *(const uint4*)(Ap + 0);
    const uint4 a1 = *(const uint4*)(Ap + 8);
    const uint4 a2 = *(const uint4*)(Ap + 16);
    const uint4 a3 = *(const uint4*)(Ap + 24);
    const uint4 a4 = *(const uint4*)(Ap + 32);
    const uint4 a5 = *(const uint4*)(Ap + 40);
    const uint4 a6 = *(const uint4*)(Ap + 48);
    const uint4 a7 = *(const uint4*)(Ap + 56);
    const uint4 b0 = *(const uint4*)(Bp + 0);
    const uint4 b1 = *(const uint4*)(Bp + 8);
    const uint4 b2 = *(const uint4*)(Bp + 16);
    const uint4 b3 = *(const uint4*)(Bp + 24);
    const uint4 b4 = *(const uint4*)(Bp + 32);
    const uint4 b5 = *(const uint4*)(Bp + 40);
    const uint4 b6 = *(const uint4*)(Bp + 48);
    const uint4 b7 = *(const uint4*)(Bp + 56);
    __syncthreads();
    *(uint4*)SWZ(sA, tr, wb + 0) = a0;
    *(uint4*)SWZ(sA, tr, wb + 16) = a1;
    *(uint4*)SWZ(sA, tr, wb + 32) = a2;
    *(uint4*)SWZ(sA, tr, wb + 48) = a3;
    *(uint4*)SWZ(sA, tr, wb + 64) = a4;
    *(uint4*)SWZ(sA, tr, wb + 80) = a5;
    *(uint4*)SWZ(sA, tr, wb + 96) = a6;
    *(uint4*)SWZ(sA, tr, wb + 112) = a7;
    *(uint4*)SWZ(sB, tr, wb + 0) = b0;
    *(uint4*)SWZ(sB, tr, wb + 16) = b1;
    *(uint4*)SWZ(sB, tr, wb + 32) = b2;
    *(uint4*)SWZ(sB, tr, wb + 48) = b3;
    *(uint4*)SWZ(sB, tr, wb + 64) = b4;
    *(uint4*)SWZ(sB, tr, wb + 80) = b5;
    *(uint4*)SWZ(sB, tr, wb + 96) = b6;
    *(uint4*)SWZ(sB, tr, wb + 112) = b7;
    __syncthreads();
#pragma unroll
    for (int kk = 0; kk < 4; kk++) {
      const int cb = kk * 64 + lgrp * 16;
      const int rA0 = wave * 32 + lane15;
      bf16x8 av0 = *(const bf16x8*)SWZ(sA, rA0, cb);
      bf16x8 av1 = *(const bf16x8*)SWZ(sA, rA0 + 16, cb);
#pragma unroll
      for (int f = 0; f < 8; f++) {
        bf16x8 wv = *(const bf16x8*)SWZ(sB, f * 16 + lane15, cb);
        acc[0][f] = __builtin_amdgcn_mfma_f32_16x16x32_bf16(av0, wv, acc[0][f], 0, 0, 0);
        acc[1][f] = __builtin_amdgcn_mfma_f32_16x16x32_bf16(av1, wv, acc[1][f], 0, 0, 0);
      }
    }
  }

  // ---- epilogue: bounce acc through LDS for coalesced stores ----
  __syncthreads();  // staging LDS dead; reuse as f32 [128][FST]
  float* fb = (float*)smem;
  const int row0w = wave * 32;
#pragma unroll
  for (int m = 0; m < 2; m++)
#pragma unroll
    for (int f = 0; f < 8; f++)
#pragma unroll
      for (int j = 0; j < 4; j++)
        fb[(row0w + m * 16 + lgrp * 4 + j) * FST + f * 16 + lane15] = acc[m][f][j];
  __syncthreads();
  const int rowg = row0 + tr;
  if (rowg < nrows) {
    const float* rp = fb + tr * FST + th;
    if (Yf) {
      float* yp = Yf + (size_t)rowg * 128 + th;
#pragma unroll
      for (int q = 0; q < 16; q++) {
        float4 v = ((const float4*)rp)[q];
        if (bias) {
          const float4 bv = ((const float4*)(bias + th))[q];
          v.x += bv.x; v.y += bv.y; v.z += bv.z; v.w += bv.w;
        }
        if (act == 1) {
          v.x = v.x > 0.f ? v.x : SLOPE * v.x; v.y = v.y > 0.f ? v.y : SLOPE * v.y;
          v.z = v.z > 0.f ? v.z : SLOPE * v.z; v.w = v.w > 0.f ? v.w : SLOPE * v.w;
        } else if (act == 2) {
          v.x = v.x > 0.f ? v.x : 0.f; v.y = v.y > 0.f ? v.y : 0.f;
          v.z = v.z > 0.f ? v.z : 0.f; v.w = v.w > 0.f ? v.w : 0.f;
        }
        ((float4*)yp)[q] = v;
      }
    } else {
      ushort_t* yp = Yb + (size_t)rowg * 128 + th;
#pragma unroll
      for (int q = 0; q < 8; q++) {
        float4 v0 = ((const float4*)rp)[2 * q];
        float4 v1 = ((const float4*)rp)[2 * q + 1];
        if (bias) {
          const float4 b0 = ((const float4*)(bias + th))[2 * q];
          const float4 b1 = ((const float4*)(bias + th))[2 * q + 1];
          v0.x += b0.x; v0.y += b0.y; v0.z += b0.z; v0.w += b0.w;
          v1.x += b1.x; v1.y += b1.y; v1.z += b1.z; v1.w += b1.w;
        }
        if (act == 1) {
          v0.x = v0.x > 0.f ? v0.x : SLOPE * v0.x; v0.y = v0.y > 0.f ? v0.y : SLOPE * v0.y;
          v0.z = v0.z > 0.f ? v0.z : SLOPE * v0.z; v0.w = v0.w > 0.f ? v0.w : SLOPE * v0.w;
          v1.x = v1.x > 0.f ? v1.x : SLOPE * v1.x; v1.y = v1.y > 0.f ? v1.y : SLOPE * v1.y;
          v1.z = v1.z > 0.f ? v1.z : SLOPE * v1.z; v1.w = v1.w > 0.f ? v1.w : SLOPE * v1.w;
        } else if (act == 2) {
          v0.x = v0.x > 0.f ? v0.x : 0.f; v0.y = v0.y > 0.f ? v0.y : 0.f;
          v0.z = v0.z > 0.f ? v0.z : 0.f; v0.w = v0.w > 0.f ? v0.w : 0.f;
          v1.x = v1.x > 0.f ? v1.x : 0.f; v1.y = v1.y > 0.f ? v1.y : 0.f;
          v1.z = v1.z > 0.f ? v1.z : 0.f; v1.w = v1.w > 0.f ? v1.w : 0.f;
        }
        uint4 o;
        o.x = pack2bf(v0.x, v0.y); o.y = pack2bf(v0.z, v0.w);
        o.z = pack2bf(v1.x, v1.y); o.w = pack2bf(v1.z, v1.w);
        ((uint4*)yp)[q] = o;
      }
    }
  }
}

// ---------------------------------------------------------------- gather (bf16)
// Wave per dst row; 4 slots x 16 lanes; slot processes pairs (j, j+4), stride 8.
// esrc2 holds (byte offset, dis[src]) -> no dependent dis load in hot loop.
__global__ __launch_bounds__(256) void gcn_gather_k(const ushort_t* __restrict__ xw,
                                                    const int* __restrict__ rowp,
                                                    const int2* __restrict__ esrc2,
                                                    const float* __restrict__ dis,
                                                    const float* __restrict__ bias,
                                                    ushort_t* __restrict__ out, int nrows) {
  const int lane = threadIdx.x & 63;
  const int row = (blockIdx.x * blockDim.x + threadIdx.x) >> 6;
  if (row >= nrows) return;
  const int slot = lane >> 4;
  const int ch = lane & 15;
  const int start = rowp[row];
  const int end = rowp[row + 1];
  const float dr = dis[row];
  const char* xwb_ = (const char*)xw;
  const int chb = ch * 16;

  f32x2 a01 = {0.f, 0.f}, a23 = {0.f, 0.f}, a45 = {0.f, 0.f}, a67 = {0.f, 0.f};
  for (int j = start + slot; j < end; j += 8) {
    const int2 e1 = esrc2[j];
    const int j2 = j + 4;
    const bool h2 = j2 < end;
    const int2 e2 = h2 ? esrc2[j2] : e1;
    const float w1 = __int_as_float(e1.y);
    const float w2 = h2 ? __int_as_float(e2.y) : 0.f;
    const uint4 v1 = *(const uint4*)(xwb_ + (size_t)(uint_t)e1.x + chb);
    const uint4 v2 = *(const uint4*)(xwb_ + (size_t)(uint_t)e2.x + chb);
    f32x2 wp1; wp1.x = w1; wp1.y = w1;
    f32x2 wp2; wp2.x = w2; wp2.y = w2;
    a01 += wp1 * u2f2(v1.x) + wp2 * u2f2(v2.x);
    a23 += wp1 * u2f2(v1.y) + wp2 * u2f2(v2.y);
    a45 += wp1 * u2f2(v1.z) + wp2 * u2f2(v2.z);
    a67 += wp1 * u2f2(v1.w) + wp2 * u2f2(v2.w);
  }
  float a0 = a01.x, a1 = a01.y, a2 = a23.x, a3 = a23.y;
  float a4 = a45.x, a5 = a45.y, a6 = a67.x, a7 = a67.y;
  a0 += __shfl_xor(a0, 16, 64); a1 += __shfl_xor(a1, 16, 64);
  a2 += __shfl_xor(a2, 16, 64); a3 += __shfl_xor(a3, 16, 64);
  a4 += __shfl_xor(a4, 16, 64); a5 += __shfl_xor(a5, 16, 64);
  a6 += __shfl_xor(a6, 16, 64); a7 += __shfl_xor(a7, 16, 64);
  a0 += __shfl_xor(a0, 32, 64); a1 += __shfl_xor(a1, 32, 64);
  a2 += __shfl_xor(a2, 32, 64); a3 += __shfl_xor(a3, 32, 64);
  a4 += __shfl_xor(a4, 32, 64); a5 += __shfl_xor(a5, 32, 64);
  a6 += __shfl_xor(a6, 32, 64); a7 += __shfl_xor(a7, 32, 64);

  if (slot == 0) {
    const float4 b0 = *(const float4*)(bias + ch * 8);
    const float4 b1 = *(const float4*)(bias + ch * 8 + 4);
    float o0 = dr * a0 + b0.x, o1 = dr * a1 + b0.y;
    float o2 = dr * a2 + b0.z, o3 = dr * a3 + b0.w;
    float o4 = dr * a4 + b1.x, o5 = dr * a5 + b1.y;
    float o6 = dr * a6 + b1.z, o7 = dr * a7 + b1.w;
    o0 = o0 > 0.f ? o0 : SLOPE * o0; o1 = o1 > 0.f ? o1 : SLOPE * o1;
    o2 = o2 > 0.f ? o2 : SLOPE * o2; o3 = o3 > 0.f ? o3 : SLOPE * o3;
    o4 = o4 > 0.f ? o4 : SLOPE * o4; o5 = o5 > 0.f ? o5 : SLOPE * o5;
    o6 = o6 > 0.f ? o6 : SLOPE * o6; o7 = o7 > 0.f ? o7 : SLOPE * o7;
    uint4 o;
    o.x = pack2bf(o0, o1); o.y = pack2bf(o2, o3);
    o.z = pack2bf(o4, o5); o.w = pack2bf(o6, o7);
    *(uint4*)(out + (size_t)row * 128 + ch * 8) = o;
  }
}

// ---------------------------------------------------------------- batchnorm
__global__ __launch_bounds__(256) void bn_stats_k(const ushort_t* __restrict__ X,
                                                  float* __restrict__ sums,
                                                  float* __restrict__ sumsq, int nrows) {
  __shared__ float ls[256], lq[256];
  const int t = threadIdx.x;
  const int c = t & 127;
  const int h = t >> 7;
  const int r0 = blockIdx.x * 256;
  const int r1 = min(r0 + 256, nrows);
  float s = 0.f, q = 0.f;
  for (int r = r0 + h; r < r1; r += 2) {
    float v = bf2f(X[(size_t)r * 128 + c]);
    s += v;
    q += v * v;
  }
  ls[t] = s;
  lq[t] = q;
  __syncthreads();
  if (t < 128) {
    s = ls[t] + ls[t + 128];
    q = lq[t] + lq[t + 128];
    atomicAdd(&sums[c], s);
    atomicAdd(&sumsq[c], q);
  }
}

__global__ void bn_finalize_k(const float* __restrict__ sums,
                              const float* __restrict__ sumsq,
                              const float* __restrict__ g,
                              const float* __restrict__ be,
                              float* __restrict__ scl, float* __restrict__ sht) {
  int c = threadIdx.x;
  float mu = sums[c] * (1.f / (float)NN);
  float var = sumsq[c] * (1.f / (float)NN) - mu * mu;
  float s = g[c] * rsqrtf(var + FEPS);
  scl[c] = s;
  sht[c] = be[c] - mu * s;
}

// fold BN affine into head weight
__global__ __launch_bounds__(128) void fold_head_k(const float* __restrict__ W,
                                                   const float* __restrict__ b,
                                                   const float* __restrict__ sclS,
                                                   const float* __restrict__ shtS,
                                                   const float* __restrict__ sclR,
                                                   const float* __restrict__ shtR,
                                                   ushort_t* __restrict__ Wf,
                                                   float* __restrict__ bf) {
  const int col = threadIdx.x;
  float acc = b[col];
  for (int k = 0; k < 256; k++) {
    const float w = W[(size_t)k * 128 + col];
    const float sc = (k < 128) ? sclS[k] : sclR[k - 128];
    const float sh = (k < 128) ? shtS[k] : shtR[k - 128];
    acc += sh * w;
    Wf[(size_t)col * 256 + k] = f2bf(sc * w);
  }
  bf[col] = acc;
}

// ---------------------------------------------------------------- launch
extern "C" void kernel_launch(void* const* d_in, const int* in_sizes, int n_in,
                              void* d_out, int out_size, void* d_ws, size_t ws_size,
                              hipStream_t stream) {
  const float* feature = (const float*)d_in[0];
  const int* sen_edge = (const int*)d_in[1];
  const int* res_edge = (const int*)d_in[2];
  const float* W_sen1 = (const float*)d_in[3];
  const float* b_sen1 = (const float*)d_in[4];
  const float* W_sen2 = (const float*)d_in[5];
  const float* b_sen2 = (const float*)d_in[6];
  const float* W_senfc = (const float*)d_in[7];
  const float* b_senfc = (const float*)d_in[8];
  const float* g_sen = (const float*)d_in[9];
  const float* be_sen = (const float*)d_in[10];
  const float* W_res1 = (const float*)d_in[11];
  const float* b_res1 = (const float*)d_in[12];
  const float* W_res2 = (const float*)d_in[13];
  const float* b_res2 = (const float*)d_in[14];
  const float* W_resfc = (const float*)d_in[15];
  const float* b_resfc = (const float*)d_in[16];
  const float* g_res = (const float*)d_in[17];
  const float* be_res = (const float*)d_in[18];
  const float* W_cell = (const float*)d_in[19];
  const float* b_cell = (const float*)d_in[20];
  const float* W_drug = (const float*)d_in[21];
  const float* b_drug = (const float*)d_in[22];
  float* out = (float*)d_out;

  const size_t NF = (size_t)NN * 128;
  char* wsb = (char*)d_ws;
  ushort_t* featb = (ushort_t*)wsb;                 // NF bf16 each
  ushort_t* x1b = featb + NF;
  ushort_t* x2b = x1b + NF;
  ushort_t* xwb = x2b + NF;
  ushort_t* xallSb = xwb + NF;
  ushort_t* xallRb = xallSb + NF;
  ushort_t* wt = xallRb + NF;                       // weight pool
  ushort_t* W1tS = wt;                              // 128*128
  ushort_t* W2tS = W1tS + 128 * 128;
  ushort_t* WfctS = W2tS + 128 * 128;               // 128*384
  ushort_t* W1tR = WfctS + 128 * 384;
  ushort_t* W2tR = W1tR + 128 * 128;
  ushort_t* WfctR = W2tR + 128 * 128;
  ushort_t* Wcellf = WfctR + 128 * 384;             // 128*256 (folded)
  ushort_t* Wdrugf = Wcellf + 128 * 256;
  float* dis = (float*)(Wdrugf + 128 * 256);        // NN
  int* rowp = (int*)(dis + NN);                     // NN+1
  int* esrc = rowp + (NN + 1);                      // EE
  int2* esrc2 = (int2*)(esrc + EE);                 // EE int2
  uint_t* ebuf = (uint_t*)(esrc2 + EE);             // EE
  int* tbl = (int*)(ebuf + EE);                     // NB*SNB
  int* off = tbl + NB * SNB;                        // NB*SNB
  int* total = off + NB * SNB;                      // NB
  int* bktoff = total + NB;                         // NB+1
  float* sums = (float*)(bktoff + NB + 1);          // 128
  float* sumsq = sums + 128;
  float* sclS = sumsq + 128;
  float* shtS = sclS + 128;
  float* sclR = shtS + 128;
  float* shtR = sclR + 128;
  float* bcellf = shtR + 128;
  float* bdrugf = bcellf + 128;

  const int MG = (NN + 127) / 128;          // 782
  const int GATH_N = (NN * 64 + 255) / 256; // 25000
  const int EB = (EE + 255) / 256;          // 6250
  const int STAT_N = (NN + 255) / 256;      // 391

  feat_cvt_k<<<(int)(NF / 8 + 255) / 256, 256, 0, stream>>>(feature, featb, (int)(NF / 8));
  WCA wa;
  wa.w[0] = {W_sen1, W1tS, 128};  wa.w[1] = {W_sen2, W2tS, 128};
  wa.w[2] = {W_senfc, WfctS, 384}; wa.w[3] = {W_res1, W1tR, 128};
  wa.w[4] = {W_res2, W2tR, 128};  wa.w[5] = {W_resfc, WfctR, 384};
  wcvt_k<<<dim3(6, 24), 128, 0, stream>>>(wa);

  struct Branch {
    const int* edge;
    ushort_t* W1t; const float* b1;
    ushort_t* W2t; const float* b2;
    ushort_t* Wfct; const float* bfc;
    const float* g; const float* be;
    ushort_t* xallb; float* scl; float* sht;
  };
  Branch br[2] = {
      {sen_edge, W1tS, b_sen1, W2tS, b_sen2, WfctS, b_senfc, g_sen, be_sen, xallSb, sclS, shtS},
      {res_edge, W1tR, b_res1, W2tR, b_res2, WfctR, b_resfc, g_res, be_res, xallRb, sclR, shtR},
  };

  for (int b = 0; b < 2; b++) {
    const int* src = br[b].edge;
    const int* dst = br[b].edge + EE;
    // CSR build: no global atomics anywhere
    sort_count_k<<<SNB, 256, 0, stream>>>(dst, tbl, EE);
    bkt_total_k<<<NB, 256, 0, stream>>>(tbl, total);
    bkt_scan_k<<<1, 512, 0, stream>>>(total, bktoff, rowp, NN, EE);
    sort_offset_k<<<NB, 256, 0, stream>>>(tbl, bktoff, off);
    sort_place_k<<<SNB, 256, 0, stream>>>(src, dst, off, ebuf, EE);
    bucket_fill2_k<<<NB, 256, 0, stream>>>(ebuf, bktoff, rowp, dis, esrc, NN);
    esrc_aug_k<<<EB, 256, 0, stream>>>(esrc, dis, esrc2, EE);
    // layer 1
    gemm_mfma_k<<<MG, 256, 0, stream>>>(featb, nullptr, nullptr, br[b].W1t, nullptr,
                                        nullptr, xwb, NN, 1, 0);
    gcn_gather_k<<<GATH_N, 256, 0, stream>>>(xwb, rowp, esrc2, dis, br[b].b1, x1b, NN);
    // layer 2
    gemm_mfma_k<<<MG, 256, 0, stream>>>(x1b, nullptr, nullptr, br[b].W2t, nullptr,
                                        nullptr, xwb, NN, 1, 0);
    gcn_gather_k<<<GATH_N, 256, 0, stream>>>(xwb, rowp, esrc2, dis, br[b].b2, x2b, NN);
    // fc
    gemm_mfma_k<<<MG, 256, 0, stream>>>(featb, x1b, x2b, br[b].Wfct, br[b].bfc,
                                        nullptr, br[b].xallb, NN, 3, 2);
    // batchnorm stats
    (void)hipMemsetAsync(sums, 0, 2 * 128 * sizeof(float), stream);
    bn_stats_k<<<STAT_N, 256, 0, stream>>>(br[b].xallb, sums, sumsq, NN);
    bn_finalize_k<<<1, 128, 0, stream>>>(sums, sumsq, br[b].g, br[b].be, br[b].scl, br[b].sht);
  }

  fold_head_k<<<1, 128, 0, stream>>>(W_cell, b_cell, sclS, shtS, sclR, shtR, Wcellf, bcellf);
  fold_head_k<<<1, 128, 0, stream>>>(W_drug, b_drug, sclS, shtS, sclR, shtR, Wdrugf, bdrugf);
  const int MGC = (NCELL + 127) / 128;
  const int MGD = (NDRUG + 127) / 128;
  gemm_mfma_k<<<MGC, 256, 0, stream>>>(xallSb, xallRb, nullptr, Wcellf, bcellf,
                                       out, nullptr, NCELL, 2, 2);
  float* outD = out + (size_t)NCELL * 128;
  gemm_mfma_k<<<MGD, 256, 0, stream>>>(xallSb + (size_t)NCELL * 128, xallRb + (size_t)NCELL * 128,
                                       nullptr, Wdrugf, bdrugf, outD, nullptr, NDRUG, 2, 2);
}